// Round 4
// baseline (107.213 us; speedup 1.0000x reference)
//
#include <hip/hip_runtime.h>
#include <hip/hip_bf16.h>

// Problem: B=4, N=512, D=1024, H=256. Inputs fp32, OUTPUT fp32 (reference returns float32).
//   o[b,n,h]     = sum_d x[b,n,d]*W1[h,d] + b1[h]                  (2048x256, K=1024)
//   out[b,i,j,c] = sum_h (o[b,i,h]*W2[c,h]) * o[b,j,h] + b2[c]     (per b,c: 512x512, K=256)
// ws footprint: 1 MB (o as bf16). u_c fragments built on the fly in stage 2.

typedef __attribute__((ext_vector_type(8))) short bf16x8;   // 8 bf16 = 4 VGPRs
typedef __attribute__((ext_vector_type(4))) float f32x4;
typedef __attribute__((ext_vector_type(2))) float f32x2;

__device__ __forceinline__ unsigned short f2bf(float f) {
    __hip_bfloat16 h = __float2bfloat16(f);   // RNE
    unsigned short s;
    __builtin_memcpy(&s, &h, 2);
    return s;
}

__device__ __forceinline__ float bf2f(unsigned short b) {
    unsigned int u = ((unsigned int)b) << 16;
    float f;
    __builtin_memcpy(&f, &u, 4);
    return f;
}

// Load 8 contiguous fp32, convert to a bf16x8 MFMA fragment.
__device__ __forceinline__ bf16x8 load_cvt8(const float* p) {
    f32x4 lo = *(const f32x4*)p;
    f32x4 hi = *(const f32x4*)(p + 4);
    bf16x8 r;
    r[0] = (short)f2bf(lo[0]); r[1] = (short)f2bf(lo[1]);
    r[2] = (short)f2bf(lo[2]); r[3] = (short)f2bf(lo[3]);
    r[4] = (short)f2bf(hi[0]); r[5] = (short)f2bf(hi[1]);
    r[6] = (short)f2bf(hi[2]); r[7] = (short)f2bf(hi[3]);
    return r;
}

// ---------------- Stage 1: o = x @ W1^T + b1 (bf16 out) ----------------
// One wave computes one 16x16 tile of o. 2048 tiles, 4 waves/block.
__global__ __launch_bounds__(256) void stage1_kernel(
    const float* __restrict__ x,    // [2048][1024] fp32
    const float* __restrict__ W1,   // [256][1024] fp32
    const float* __restrict__ b1,   // [256] fp32
    unsigned short* __restrict__ o) // [2048][256] bf16
{
    const int lane = threadIdx.x & 63;
    const int wave = threadIdx.x >> 6;
    const int tile = blockIdx.x * 4 + wave;        // 0..2047
    const int mTile = tile >> 4;                   // 128 m-tiles
    const int hTile = tile & 15;                   // 16 h-tiles
    const int m0 = mTile * 16;
    const int h0 = hTile * 16;
    const int l15 = lane & 15;
    const int quad = lane >> 4;

    // A-frag: rows of x; B-frag: rows of W1 (K-contiguous). [idx=lane&15][k=quad*8+j]
    const float* xrow = x  + (m0 + l15) * 1024 + quad * 8;
    const float* wrow = W1 + (h0 + l15) * 1024 + quad * 8;

    f32x4 acc = {0.f, 0.f, 0.f, 0.f};
    #pragma unroll 4
    for (int k = 0; k < 1024; k += 32) {
        bf16x8 a = load_cvt8(xrow + k);
        bf16x8 b = load_cvt8(wrow + k);
        acc = __builtin_amdgcn_mfma_f32_16x16x32_bf16(a, b, acc, 0, 0, 0);
    }

    // C/D layout: col(h) = lane&15, row(m) = quad*4 + reg
    const int h = h0 + l15;
    const float bias = b1[h];
    #pragma unroll
    for (int r = 0; r < 4; ++r) {
        const int row = m0 + quad * 4 + r;
        o[row * 256 + h] = f2bf(acc[r] + bias);
    }
}

// ---------------- Stage 2: out[b,i,j,c] = (o[b,i,:]*W2[c,:]) . o[b,j,:] + b2[c] ----------------
// One wave computes one 16x16 (i,j) tile for one b, both c channels.
// u_c A-fragments built on the fly: a_c[j] = bf16(f32(o_i[j]) * W2[c, k(j)]).
__global__ __launch_bounds__(256) void stage2_kernel(
    const unsigned short* __restrict__ o,    // [4][512][256] bf16
    const float* __restrict__ W2,            // [2][256] fp32
    const float* __restrict__ b2,            // [2] fp32
    float* __restrict__ out)                 // [4][512][512][2] fp32
{
    const int lane = threadIdx.x & 63;
    const int wave = threadIdx.x >> 6;
    const int tile = blockIdx.x * 4 + wave;        // 0..4095
    const int b   = tile >> 10;                    // 4 batches
    const int rem = tile & 1023;
    const int iT  = rem >> 5;                      // 32 i-tiles
    const int jT  = rem & 31;                      // 32 j-tiles
    const int l15 = lane & 15;
    const int quad = lane >> 4;

    const unsigned short* irow = o + ((b * 512 + iT * 16 + l15) * 256) + quad * 8;
    const unsigned short* jrow = o + ((b * 512 + jT * 16 + l15) * 256) + quad * 8;
    const float* w20p = W2 + quad * 8;            // c=0 row, this lane's k-slice
    const float* w21p = W2 + 256 + quad * 8;      // c=1 row

    f32x4 acc0 = {0.f, 0.f, 0.f, 0.f};
    f32x4 acc1 = {0.f, 0.f, 0.f, 0.f};
    #pragma unroll
    for (int k = 0; k < 256; k += 32) {
        bf16x8 oi = *(const bf16x8*)(irow + k);
        bf16x8 oj = *(const bf16x8*)(jrow + k);
        f32x4 wlo0 = *(const f32x4*)(w20p + k);
        f32x4 whi0 = *(const f32x4*)(w20p + k + 4);
        f32x4 wlo1 = *(const f32x4*)(w21p + k);
        f32x4 whi1 = *(const f32x4*)(w21p + k + 4);
        bf16x8 a0, a1;
        #pragma unroll
        for (int j = 0; j < 4; ++j) {
            const float olo = bf2f((unsigned short)oi[j]);
            const float ohi = bf2f((unsigned short)oi[4 + j]);
            a0[j]     = (short)f2bf(olo * wlo0[j]);
            a0[4 + j] = (short)f2bf(ohi * whi0[j]);
            a1[j]     = (short)f2bf(olo * wlo1[j]);
            a1[4 + j] = (short)f2bf(ohi * whi1[j]);
        }
        acc0 = __builtin_amdgcn_mfma_f32_16x16x32_bf16(a0, oj, acc0, 0, 0, 0);
        acc1 = __builtin_amdgcn_mfma_f32_16x16x32_bf16(a1, oj, acc1, 0, 0, 0);
    }

    const float bias0 = b2[0];
    const float bias1 = b2[1];
    const int j = jT * 16 + l15;                   // n-index = lane&15 (second operand)
    #pragma unroll
    for (int r = 0; r < 4; ++r) {
        const int i = iT * 16 + quad * 4 + r;      // m-index = quad*4+reg (first operand)
        f32x2 v;
        v[0] = acc0[r] + bias0;                    // c = 0
        v[1] = acc1[r] + bias1;                    // c = 1
        *(f32x2*)(out + (((b * 512 + i) * 512) + j) * 2) = v;   // fp32 pair, 8B store
    }
}

extern "C" void kernel_launch(void* const* d_in, const int* in_sizes, int n_in,
                              void* d_out, int out_size, void* d_ws, size_t ws_size,
                              hipStream_t stream) {
    const float* x  = (const float*)d_in[0];   // [4,512,1024] fp32
    const float* W1 = (const float*)d_in[1];   // [256,1024] fp32
    const float* b1 = (const float*)d_in[2];   // [256] fp32
    const float* W2 = (const float*)d_in[3];   // [2,256] fp32
    const float* b2 = (const float*)d_in[4];   // [2] fp32
    float* out = (float*)d_out;                // [4,512,512,2] fp32

    // workspace: o only — 2048*256 bf16 = 1 MB
    unsigned short* o = (unsigned short*)d_ws;

    stage1_kernel<<<512, 256, 0, stream>>>(x, W1, b1, o);
    stage2_kernel<<<1024, 256, 0, stream>>>(o, W2, b2, out);
}

// Round 5
// 92.964 us; speedup vs baseline: 1.1533x; 1.1533x over previous
//
#include <hip/hip_runtime.h>
#include <hip/hip_bf16.h>

// Problem: B=4, N=512, D=1024, H=256. Inputs fp32, OUTPUT fp32.
//   o[b,n,h]     = sum_d x[b,n,d]*W1[h,d] + b1[h]                  (2048x256, K=1024)
//   out[b,i,j,c] = sum_h (o[b,i,h]*W2[c,h]) * o[b,j,h] + b2[c]     (per b,c: 512x512, K=256)
//
// Stage 1 = split-K LDS-tiled MFMA GEMM (fixes round-4's latency-bound 4KB-strided
// fragment loads + 256 MB redundant fp32 traffic):
//   s1_gemm:  256 blocks = 32 mTiles(64 rows) x 8 kChunks(128). Coalesced float4
//             global loads -> cvt bf16 -> padded LDS -> MFMA -> fp32 partials P.
//   s1_reduce: o = bf16(sum_k P + b1).
// Stage 2 unchanged from round 4 (isolating the experiment).

typedef __attribute__((ext_vector_type(8))) short bf16x8;   // 8 bf16 = 4 VGPRs
typedef __attribute__((ext_vector_type(4))) short bf16x4;   // 4 bf16 = 2 VGPRs
typedef __attribute__((ext_vector_type(4))) float f32x4;
typedef __attribute__((ext_vector_type(2))) float f32x2;

__device__ __forceinline__ unsigned short f2bf(float f) {
    __hip_bfloat16 h = __float2bfloat16(f);   // RNE
    unsigned short s;
    __builtin_memcpy(&s, &h, 2);
    return s;
}

__device__ __forceinline__ float bf2f(unsigned short b) {
    unsigned int u = ((unsigned int)b) << 16;
    float f;
    __builtin_memcpy(&f, &u, 4);
    return f;
}

__device__ __forceinline__ bf16x4 cvt4(f32x4 v) {
    bf16x4 r;
    r[0] = (short)f2bf(v[0]); r[1] = (short)f2bf(v[1]);
    r[2] = (short)f2bf(v[2]); r[3] = (short)f2bf(v[3]);
    return r;
}

// ---------------- Stage 1a: split-K GEMM -> fp32 partials ----------------
// Block = 256 threads (4 waves). kT = blockIdx&7 (same-kT blocks share the same
// W1 chunk and land round-robin on the same XCD -> L2-resident). mT = blockIdx>>3.
// LDS rows padded to 72 elements (144 B: 16B-aligned for ds_read_b128, 36-bank
// stride breaks the 256B power-of-2 row pathology).
#define S1_LD 72

__global__ __launch_bounds__(256) void s1_gemm(
    const float* __restrict__ x,    // [2048][1024]
    const float* __restrict__ W1,   // [256][1024]
    float* __restrict__ P)          // [8][2048][256] partials
{
    __shared__ unsigned short xs[64 * S1_LD];    // 9216 B
    __shared__ unsigned short ws_[256 * S1_LD];  // 36864 B
    const int tid  = threadIdx.x;
    const int lane = tid & 63;
    const int wave = tid >> 6;
    const int kT = blockIdx.x & 7;
    const int mT = blockIdx.x >> 3;
    const int l15 = lane & 15;
    const int quad = lane >> 4;

    f32x4 acc[4][4];   // [f = m-frag][g = h-frag], wave owns h range wave*64..+63
    #pragma unroll
    for (int f = 0; f < 4; ++f)
        #pragma unroll
        for (int g = 0; g < 4; ++g)
            acc[f][g] = (f32x4){0.f, 0.f, 0.f, 0.f};

    for (int p = 0; p < 2; ++p) {                // two 64-wide K phases per chunk
        const int k0 = kT * 128 + p * 64;
        if (p) __syncthreads();                  // drain MFMA reads before overwrite

        // stage x tile: 64 rows x 64 cols fp32 = 1024 float4, 4 per thread.
        // lanes 0..15 cover one row's 256 B contiguously -> coalesced.
        #pragma unroll
        for (int i = 0; i < 4; ++i) {
            const int idx = i * 256 + tid;       // 0..1023
            const int row = idx >> 4;
            const int c4  = idx & 15;
            f32x4 v = *(const f32x4*)(x + (mT * 64 + row) * 1024 + k0 + c4 * 4);
            *(bf16x4*)(&xs[row * S1_LD + c4 * 4]) = cvt4(v);
        }
        // stage W1 tile: 256 rows x 64 cols fp32 = 4096 float4, 16 per thread.
        #pragma unroll 8
        for (int i = 0; i < 16; ++i) {
            const int idx = i * 256 + tid;       // 0..4095
            const int row = idx >> 4;
            const int c4  = idx & 15;
            f32x4 v = *(const f32x4*)(W1 + row * 1024 + k0 + c4 * 4);
            *(bf16x4*)(&ws_[row * S1_LD + c4 * 4]) = cvt4(v);
        }
        __syncthreads();

        #pragma unroll
        for (int s = 0; s < 2; ++s) {            // two k32 steps per phase
            bf16x8 a[4], b[4];
            #pragma unroll
            for (int f = 0; f < 4; ++f)
                a[f] = *(const bf16x8*)(&xs[(f * 16 + l15) * S1_LD + s * 32 + quad * 8]);
            #pragma unroll
            for (int g = 0; g < 4; ++g)
                b[g] = *(const bf16x8*)(&ws_[(wave * 64 + g * 16 + l15) * S1_LD + s * 32 + quad * 8]);
            #pragma unroll
            for (int f = 0; f < 4; ++f)
                #pragma unroll
                for (int g = 0; g < 4; ++g)
                    acc[f][g] = __builtin_amdgcn_mfma_f32_16x16x32_bf16(a[f], b[g], acc[f][g], 0, 0, 0);
        }
    }

    // partial write: P[kT][m][h]; D layout col(h)=lane&15, row(m)=quad*4+reg.
    float* Pk = P + kT * (2048 * 256);
    #pragma unroll
    for (int f = 0; f < 4; ++f) {
        #pragma unroll
        for (int g = 0; g < 4; ++g) {
            const int h = wave * 64 + g * 16 + l15;
            #pragma unroll
            for (int r = 0; r < 4; ++r) {
                const int m = mT * 64 + f * 16 + quad * 4 + r;
                Pk[m * 256 + h] = acc[f][g][r];
            }
        }
    }
}

// ---------------- Stage 1b: o = bf16(sum_k P + b1) ----------------
__global__ __launch_bounds__(256) void s1_reduce(
    const float* __restrict__ P,     // [8][2048][256]
    const float* __restrict__ b1,    // [256]
    unsigned short* __restrict__ o)  // [2048][256] bf16
{
    const int e4 = blockIdx.x * 256 + threadIdx.x;   // 0..131071, 4 elems each
    f32x4 s = *(const f32x4*)(P + e4 * 4);
    #pragma unroll
    for (int kt = 1; kt < 8; ++kt)
        s += *(const f32x4*)(P + kt * (2048 * 256) + e4 * 4);
    s += *(const f32x4*)(b1 + (e4 & 63) * 4);
    *(bf16x4*)(o + e4 * 4) = cvt4(s);
}

// ---------------- Stage 2: out[b,i,j,c] = (o[b,i,:]*W2[c,:]) . o[b,j,:] + b2[c] ----------------
// UNCHANGED from round 4. One wave per 16x16 (i,j) tile, both c channels;
// u_c A-fragments built on the fly.
__global__ __launch_bounds__(256) void stage2_kernel(
    const unsigned short* __restrict__ o,    // [4][512][256] bf16
    const float* __restrict__ W2,            // [2][256] fp32
    const float* __restrict__ b2,            // [2] fp32
    float* __restrict__ out)                 // [4][512][512][2] fp32
{
    const int lane = threadIdx.x & 63;
    const int wave = threadIdx.x >> 6;
    const int tile = blockIdx.x * 4 + wave;        // 0..4095
    const int b   = tile >> 10;
    const int rem = tile & 1023;
    const int iT  = rem >> 5;
    const int jT  = rem & 31;
    const int l15 = lane & 15;
    const int quad = lane >> 4;

    const unsigned short* irow = o + ((b * 512 + iT * 16 + l15) * 256) + quad * 8;
    const unsigned short* jrow = o + ((b * 512 + jT * 16 + l15) * 256) + quad * 8;
    const float* w20p = W2 + quad * 8;
    const float* w21p = W2 + 256 + quad * 8;

    f32x4 acc0 = {0.f, 0.f, 0.f, 0.f};
    f32x4 acc1 = {0.f, 0.f, 0.f, 0.f};
    #pragma unroll
    for (int k = 0; k < 256; k += 32) {
        bf16x8 oi = *(const bf16x8*)(irow + k);
        bf16x8 oj = *(const bf16x8*)(jrow + k);
        f32x4 wlo0 = *(const f32x4*)(w20p + k);
        f32x4 whi0 = *(const f32x4*)(w20p + k + 4);
        f32x4 wlo1 = *(const f32x4*)(w21p + k);
        f32x4 whi1 = *(const f32x4*)(w21p + k + 4);
        bf16x8 a0, a1;
        #pragma unroll
        for (int j = 0; j < 4; ++j) {
            const float olo = bf2f((unsigned short)oi[j]);
            const float ohi = bf2f((unsigned short)oi[4 + j]);
            a0[j]     = (short)f2bf(olo * wlo0[j]);
            a0[4 + j] = (short)f2bf(ohi * whi0[j]);
            a1[j]     = (short)f2bf(olo * wlo1[j]);
            a1[4 + j] = (short)f2bf(ohi * whi1[j]);
        }
        acc0 = __builtin_amdgcn_mfma_f32_16x16x32_bf16(a0, oj, acc0, 0, 0, 0);
        acc1 = __builtin_amdgcn_mfma_f32_16x16x32_bf16(a1, oj, acc1, 0, 0, 0);
    }

    const float bias0 = b2[0];
    const float bias1 = b2[1];
    const int j = jT * 16 + l15;
    #pragma unroll
    for (int r = 0; r < 4; ++r) {
        const int i = iT * 16 + quad * 4 + r;
        f32x2 v;
        v[0] = acc0[r] + bias0;
        v[1] = acc1[r] + bias1;
        *(f32x2*)(out + (((b * 512 + i) * 512) + j) * 2) = v;
    }
}

extern "C" void kernel_launch(void* const* d_in, const int* in_sizes, int n_in,
                              void* d_out, int out_size, void* d_ws, size_t ws_size,
                              hipStream_t stream) {
    const float* x  = (const float*)d_in[0];   // [4,512,1024] fp32
    const float* W1 = (const float*)d_in[1];   // [256,1024] fp32
    const float* b1 = (const float*)d_in[2];   // [256] fp32
    const float* W2 = (const float*)d_in[3];   // [2,256] fp32
    const float* b2 = (const float*)d_in[4];   // [2] fp32
    float* out = (float*)d_out;                // [4,512,512,2] fp32

    // ws layout: o bf16 [2048][256] = 1 MB @ 0; P fp32 [8][2048][256] = 16 MB @ 1 MB
    unsigned short* o = (unsigned short*)d_ws;
    float* P = (float*)((char*)d_ws + (1u << 20));

    s1_gemm  <<<256, 256, 0, stream>>>(x, W1, P);
    s1_reduce<<<512, 256, 0, stream>>>(P, b1, o);
    stage2_kernel<<<1024, 256, 0, stream>>>(o, W2, b2, out);
}

// Round 6
// 86.623 us; speedup vs baseline: 1.2377x; 1.0732x over previous
//
#include <hip/hip_runtime.h>
#include <hip/hip_bf16.h>

// Problem: B=4, N=512, D=1024, H=256. Inputs fp32, OUTPUT fp32.
//   o[b,n,h]     = sum_d x[b,n,d]*W1[h,d] + b1[h]                  (2048x256, K=1024)
//   out[b,i,j,c] = sum_h (o[b,i,h]*W2[c,h]) * o[b,j,h] + b2[c]     (per b,c: 512x512, K=256)
//
// s1_gemm / s1_reduce: unchanged from round 5 (passing, ~8+3 us).
// stage2 v2: 64x64 supertile per block, j-rows staged in LDS (shared by 4 waves),
// i-fragments + on-the-fly u_c build amortized over 4 j-frags (VALU/MFMA /4,
// global o traffic 64 MB -> ~18 MB).

typedef __attribute__((ext_vector_type(8))) short bf16x8;   // 8 bf16 = 4 VGPRs
typedef __attribute__((ext_vector_type(4))) short bf16x4;   // 4 bf16 = 2 VGPRs
typedef __attribute__((ext_vector_type(4))) float f32x4;
typedef __attribute__((ext_vector_type(2))) float f32x2;

__device__ __forceinline__ unsigned short f2bf(float f) {
    __hip_bfloat16 h = __float2bfloat16(f);   // RNE
    unsigned short s;
    __builtin_memcpy(&s, &h, 2);
    return s;
}

__device__ __forceinline__ float bf2f(unsigned short b) {
    unsigned int u = ((unsigned int)b) << 16;
    float f;
    __builtin_memcpy(&f, &u, 4);
    return f;
}

__device__ __forceinline__ bf16x4 cvt4(f32x4 v) {
    bf16x4 r;
    r[0] = (short)f2bf(v[0]); r[1] = (short)f2bf(v[1]);
    r[2] = (short)f2bf(v[2]); r[3] = (short)f2bf(v[3]);
    return r;
}

// ---------------- Stage 1a: split-K GEMM -> fp32 partials (unchanged) ----------------
#define S1_LD 72

__global__ __launch_bounds__(256) void s1_gemm(
    const float* __restrict__ x,    // [2048][1024]
    const float* __restrict__ W1,   // [256][1024]
    float* __restrict__ P)          // [8][2048][256] partials
{
    __shared__ unsigned short xs[64 * S1_LD];    // 9216 B
    __shared__ unsigned short ws_[256 * S1_LD];  // 36864 B
    const int tid  = threadIdx.x;
    const int lane = tid & 63;
    const int wave = tid >> 6;
    const int kT = blockIdx.x & 7;
    const int mT = blockIdx.x >> 3;
    const int l15 = lane & 15;
    const int quad = lane >> 4;

    f32x4 acc[4][4];
    #pragma unroll
    for (int f = 0; f < 4; ++f)
        #pragma unroll
        for (int g = 0; g < 4; ++g)
            acc[f][g] = (f32x4){0.f, 0.f, 0.f, 0.f};

    for (int p = 0; p < 2; ++p) {
        const int k0 = kT * 128 + p * 64;
        if (p) __syncthreads();

        #pragma unroll
        for (int i = 0; i < 4; ++i) {
            const int idx = i * 256 + tid;
            const int row = idx >> 4;
            const int c4  = idx & 15;
            f32x4 v = *(const f32x4*)(x + (mT * 64 + row) * 1024 + k0 + c4 * 4);
            *(bf16x4*)(&xs[row * S1_LD + c4 * 4]) = cvt4(v);
        }
        #pragma unroll 8
        for (int i = 0; i < 16; ++i) {
            const int idx = i * 256 + tid;
            const int row = idx >> 4;
            const int c4  = idx & 15;
            f32x4 v = *(const f32x4*)(W1 + row * 1024 + k0 + c4 * 4);
            *(bf16x4*)(&ws_[row * S1_LD + c4 * 4]) = cvt4(v);
        }
        __syncthreads();

        #pragma unroll
        for (int s = 0; s < 2; ++s) {
            bf16x8 a[4], b[4];
            #pragma unroll
            for (int f = 0; f < 4; ++f)
                a[f] = *(const bf16x8*)(&xs[(f * 16 + l15) * S1_LD + s * 32 + quad * 8]);
            #pragma unroll
            for (int g = 0; g < 4; ++g)
                b[g] = *(const bf16x8*)(&ws_[(wave * 64 + g * 16 + l15) * S1_LD + s * 32 + quad * 8]);
            #pragma unroll
            for (int f = 0; f < 4; ++f)
                #pragma unroll
                for (int g = 0; g < 4; ++g)
                    acc[f][g] = __builtin_amdgcn_mfma_f32_16x16x32_bf16(a[f], b[g], acc[f][g], 0, 0, 0);
        }
    }

    float* Pk = P + kT * (2048 * 256);
    #pragma unroll
    for (int f = 0; f < 4; ++f) {
        #pragma unroll
        for (int g = 0; g < 4; ++g) {
            const int h = wave * 64 + g * 16 + l15;
            #pragma unroll
            for (int r = 0; r < 4; ++r) {
                const int m = mT * 64 + f * 16 + quad * 4 + r;
                Pk[m * 256 + h] = acc[f][g][r];
            }
        }
    }
}

// ---------------- Stage 1b: o = bf16(sum_k P + b1) (unchanged) ----------------
__global__ __launch_bounds__(256) void s1_reduce(
    const float* __restrict__ P,     // [8][2048][256]
    const float* __restrict__ b1,    // [256]
    unsigned short* __restrict__ o)  // [2048][256] bf16
{
    const int e4 = blockIdx.x * 256 + threadIdx.x;
    f32x4 s = *(const f32x4*)(P + e4 * 4);
    #pragma unroll
    for (int kt = 1; kt < 8; ++kt)
        s += *(const f32x4*)(P + kt * (2048 * 256) + e4 * 4);
    s += *(const f32x4*)(b1 + (e4 & 63) * 4);
    *(bf16x4*)(o + e4 * 4) = cvt4(s);
}

// ---------------- Stage 2 v2: 64x64 supertile, LDS j-rows ----------------
// Block = 4 waves; grid 256 = b(4) x iS(8) x jS(8). Wave w owns i-rows
// [iS*64 + w*16, +16) x all 64 j. u_c fragments built once per k-step,
// reused across 4 j-fragments and both channels.
#define S2_LD 264   // shorts per LDS row (256 + 8 pad; lane stride = 132 dwords = 4 banks)

__global__ __launch_bounds__(256) void stage2_kernel(
    const unsigned short* __restrict__ o,    // [4][512][256] bf16
    const float* __restrict__ W2,            // [2][256] fp32
    const float* __restrict__ b2,            // [2] fp32
    float* __restrict__ out)                 // [4][512][512][2] fp32
{
    __shared__ unsigned short js[64 * S2_LD];   // 33792 shorts = 67584 B? NO: 64*264*2 = 33792 B
    const int tid  = threadIdx.x;
    const int lane = tid & 63;
    const int wave = tid >> 6;
    const int blk  = blockIdx.x;        // 0..255
    const int b  = blk >> 6;            // 4
    const int iS = (blk >> 3) & 7;      // 8
    const int jS = blk & 7;             // 8
    const int l15 = lane & 15;
    const int quad = lane >> 4;

    // Stage j-rows o[b][jS*64 .. +63][0:256] into LDS (coalesced 16B copies).
    const unsigned short* jbase = o + (b * 512 + jS * 64) * 256;
    #pragma unroll
    for (int i = 0; i < 8; ++i) {
        const int idx = i * 256 + tid;      // 0..2047 = 64 rows x 32 chunks
        const int row = idx >> 5;
        const int c8  = idx & 31;
        *(bf16x8*)(&js[row * S2_LD + c8 * 8]) = *(const bf16x8*)(jbase + row * 256 + c8 * 8);
    }
    __syncthreads();

    const unsigned short* irow = o + ((b * 512 + iS * 64 + wave * 16 + l15) * 256) + quad * 8;
    const float* w20p = W2 + quad * 8;
    const float* w21p = W2 + 256 + quad * 8;

    f32x4 acc0[4], acc1[4];
    #pragma unroll
    for (int g = 0; g < 4; ++g) {
        acc0[g] = (f32x4){0.f, 0.f, 0.f, 0.f};
        acc1[g] = (f32x4){0.f, 0.f, 0.f, 0.f};
    }

    #pragma unroll
    for (int s = 0; s < 8; ++s) {
        const int k = s * 32;
        bf16x8 oi = *(const bf16x8*)(irow + k);
        f32x4 wlo0 = *(const f32x4*)(w20p + k);
        f32x4 whi0 = *(const f32x4*)(w20p + k + 4);
        f32x4 wlo1 = *(const f32x4*)(w21p + k);
        f32x4 whi1 = *(const f32x4*)(w21p + k + 4);
        bf16x8 a0, a1;
        #pragma unroll
        for (int j = 0; j < 4; ++j) {
            const float olo = bf2f((unsigned short)oi[j]);
            const float ohi = bf2f((unsigned short)oi[4 + j]);
            a0[j]     = (short)f2bf(olo * wlo0[j]);
            a0[4 + j] = (short)f2bf(ohi * whi0[j]);
            a1[j]     = (short)f2bf(olo * wlo1[j]);
            a1[4 + j] = (short)f2bf(ohi * whi1[j]);
        }
        #pragma unroll
        for (int g = 0; g < 4; ++g) {
            bf16x8 bj = *(const bf16x8*)(&js[(g * 16 + l15) * S2_LD + k + quad * 8]);
            acc0[g] = __builtin_amdgcn_mfma_f32_16x16x32_bf16(a0, bj, acc0[g], 0, 0, 0);
            acc1[g] = __builtin_amdgcn_mfma_f32_16x16x32_bf16(a1, bj, acc1[g], 0, 0, 0);
        }
    }

    const float bias0 = b2[0];
    const float bias1 = b2[1];
    #pragma unroll
    for (int g = 0; g < 4; ++g) {
        const int j = jS * 64 + g * 16 + l15;           // n-index = lane&15
        #pragma unroll
        for (int r = 0; r < 4; ++r) {
            const int i = iS * 64 + wave * 16 + quad * 4 + r;   // m-index = quad*4+reg
            f32x2 v;
            v[0] = acc0[g][r] + bias0;
            v[1] = acc1[g][r] + bias1;
            *(f32x2*)(out + (((b * 512 + i) * 512) + j) * 2) = v;
        }
    }
}

extern "C" void kernel_launch(void* const* d_in, const int* in_sizes, int n_in,
                              void* d_out, int out_size, void* d_ws, size_t ws_size,
                              hipStream_t stream) {
    const float* x  = (const float*)d_in[0];   // [4,512,1024] fp32
    const float* W1 = (const float*)d_in[1];   // [256,1024] fp32
    const float* b1 = (const float*)d_in[2];   // [256] fp32
    const float* W2 = (const float*)d_in[3];   // [2,256] fp32
    const float* b2 = (const float*)d_in[4];   // [2] fp32
    float* out = (float*)d_out;                // [4,512,512,2] fp32

    // ws layout: o bf16 [2048][256] = 1 MB @ 0; P fp32 [8][2048][256] = 16 MB @ 1 MB
    unsigned short* o = (unsigned short*)d_ws;
    float* P = (float*)((char*)d_ws + (1u << 20));

    s1_gemm  <<<256, 256, 0, stream>>>(x, W1, P);
    s1_reduce<<<512, 256, 0, stream>>>(P, b1, o);
    stage2_kernel<<<256, 256, 0, stream>>>(o, W2, b2, out);
}

// Round 7
// 84.366 us; speedup vs baseline: 1.2708x; 1.0268x over previous
//
#include <hip/hip_runtime.h>
#include <hip/hip_bf16.h>

// Problem: B=4, N=512, D=1024, H=256. Inputs fp32, OUTPUT fp32.
//   o[b,n,h]     = sum_d x[b,n,d]*W1[h,d] + b1[h]                  (2048x256, K=1024)
//   out[b,i,j,c] = sum_h (o[b,i,h]*W2[c,h]) * o[b,j,h] + b2[c]     (per b,c: 512x512, K=256)
//
// R6: s1_gemm v2 — 512 blocks (64 mT x 8 kT, 32-row m-tiles, 2 blocks/CU) and
// bf16 split-K partials (P traffic 32 MB -> 16 MB round-trip). s1_reduce reads
// bf16 P. stage2 (64x64 supertile, LDS j-rows) unchanged from passing round 6.

typedef __attribute__((ext_vector_type(8))) short bf16x8;   // 8 bf16 = 4 VGPRs
typedef __attribute__((ext_vector_type(4))) short bf16x4;   // 4 bf16 = 2 VGPRs
typedef __attribute__((ext_vector_type(4))) float f32x4;
typedef __attribute__((ext_vector_type(2))) float f32x2;

__device__ __forceinline__ unsigned short f2bf(float f) {
    __hip_bfloat16 h = __float2bfloat16(f);   // RNE
    unsigned short s;
    __builtin_memcpy(&s, &h, 2);
    return s;
}

__device__ __forceinline__ float bf2f(unsigned short b) {
    unsigned int u = ((unsigned int)b) << 16;
    float f;
    __builtin_memcpy(&f, &u, 4);
    return f;
}

__device__ __forceinline__ bf16x4 cvt4(f32x4 v) {
    bf16x4 r;
    r[0] = (short)f2bf(v[0]); r[1] = (short)f2bf(v[1]);
    r[2] = (short)f2bf(v[2]); r[3] = (short)f2bf(v[3]);
    return r;
}

// ---------------- Stage 1a: split-K GEMM -> bf16 partials ----------------
// 512 blocks = 64 mTiles(32 rows) x 8 kChunks(128). 4 waves; wave owns h-range
// wave*64..+63. LDS rows padded to 72 shorts (16B-aligned, stride 36 banks).
#define S1_LD 72

__global__ __launch_bounds__(256) void s1_gemm(
    const float* __restrict__ x,        // [2048][1024]
    const float* __restrict__ W1,       // [256][1024]
    unsigned short* __restrict__ P)     // [8][2048][256] bf16 partials
{
    __shared__ unsigned short xs[32 * S1_LD];    // 4608 B
    __shared__ unsigned short ws_[256 * S1_LD];  // 36864 B
    const int tid  = threadIdx.x;
    const int lane = tid & 63;
    const int wave = tid >> 6;
    const int kT = blockIdx.x & 7;
    const int mT = blockIdx.x >> 3;              // 0..63, 32 rows each
    const int l15 = lane & 15;
    const int quad = lane >> 4;

    f32x4 acc[2][4];   // [f = m-frag(2)][g = h-frag(4)]
    #pragma unroll
    for (int f = 0; f < 2; ++f)
        #pragma unroll
        for (int g = 0; g < 4; ++g)
            acc[f][g] = (f32x4){0.f, 0.f, 0.f, 0.f};

    for (int p = 0; p < 2; ++p) {                // two 64-wide K phases
        const int k0 = kT * 128 + p * 64;
        if (p) __syncthreads();

        // stage x tile: 32 rows x 64 cols fp32 = 512 float4, 2 per thread
        #pragma unroll
        for (int i = 0; i < 2; ++i) {
            const int idx = i * 256 + tid;       // 0..511
            const int row = idx >> 4;
            const int c4  = idx & 15;
            f32x4 v = *(const f32x4*)(x + (mT * 32 + row) * 1024 + k0 + c4 * 4);
            *(bf16x4*)(&xs[row * S1_LD + c4 * 4]) = cvt4(v);
        }
        // stage W1 tile: 256 rows x 64 cols fp32 = 4096 float4, 16 per thread
        #pragma unroll 8
        for (int i = 0; i < 16; ++i) {
            const int idx = i * 256 + tid;       // 0..4095
            const int row = idx >> 4;
            const int c4  = idx & 15;
            f32x4 v = *(const f32x4*)(W1 + row * 1024 + k0 + c4 * 4);
            *(bf16x4*)(&ws_[row * S1_LD + c4 * 4]) = cvt4(v);
        }
        __syncthreads();

        #pragma unroll
        for (int s = 0; s < 2; ++s) {            // two k32 steps per phase
            bf16x8 a[2], b[4];
            #pragma unroll
            for (int f = 0; f < 2; ++f)
                a[f] = *(const bf16x8*)(&xs[(f * 16 + l15) * S1_LD + s * 32 + quad * 8]);
            #pragma unroll
            for (int g = 0; g < 4; ++g)
                b[g] = *(const bf16x8*)(&ws_[(wave * 64 + g * 16 + l15) * S1_LD + s * 32 + quad * 8]);
            #pragma unroll
            for (int f = 0; f < 2; ++f)
                #pragma unroll
                for (int g = 0; g < 4; ++g)
                    acc[f][g] = __builtin_amdgcn_mfma_f32_16x16x32_bf16(a[f], b[g], acc[f][g], 0, 0, 0);
        }
    }

    // partial write (bf16): P[kT][m][h]; D layout col(h)=lane&15, row(m)=quad*4+reg.
    unsigned short* Pk = P + kT * (2048 * 256);
    #pragma unroll
    for (int f = 0; f < 2; ++f) {
        #pragma unroll
        for (int g = 0; g < 4; ++g) {
            const int h = wave * 64 + g * 16 + l15;
            #pragma unroll
            for (int r = 0; r < 4; ++r) {
                const int m = mT * 32 + f * 16 + quad * 4 + r;
                Pk[m * 256 + h] = f2bf(acc[f][g][r]);
            }
        }
    }
}

// ---------------- Stage 1b: o = bf16(sum_k P + b1) ----------------
// 256 blocks x 256 threads; each thread reduces 8 consecutive elements.
__global__ __launch_bounds__(256) void s1_reduce(
    const unsigned short* __restrict__ P,  // [8][2048][256] bf16
    const float* __restrict__ b1,          // [256]
    unsigned short* __restrict__ o)        // [2048][256] bf16
{
    const int base = (blockIdx.x * 256 + threadIdx.x) * 8;   // elem idx, 8 each
    const int h0 = base & 255;                               // 0,8,...,248
    float s[8];
    {
        f32x4 blo = *(const f32x4*)(b1 + h0);
        f32x4 bhi = *(const f32x4*)(b1 + h0 + 4);
        #pragma unroll
        for (int j = 0; j < 4; ++j) { s[j] = blo[j]; s[4 + j] = bhi[j]; }
    }
    #pragma unroll
    for (int kt = 0; kt < 8; ++kt) {
        bf16x8 v = *(const bf16x8*)(P + kt * (2048 * 256) + base);
        #pragma unroll
        for (int j = 0; j < 8; ++j)
            s[j] += bf2f((unsigned short)v[j]);
    }
    bf16x8 r;
    #pragma unroll
    for (int j = 0; j < 8; ++j)
        r[j] = (short)f2bf(s[j]);
    *(bf16x8*)(o + base) = r;
}

// ---------------- Stage 2: 64x64 supertile, LDS j-rows (unchanged) ----------------
// Block = 4 waves; grid 256 = b(4) x iS(8) x jS(8). Wave w owns i-rows
// [iS*64 + w*16, +16) x all 64 j. u_c fragments built once per k-step,
// reused across 4 j-fragments and both channels.
#define S2_LD 264   // shorts per LDS row (256 + 8 pad); 64*264*2 = 33792 B

__global__ __launch_bounds__(256) void stage2_kernel(
    const unsigned short* __restrict__ o,    // [4][512][256] bf16
    const float* __restrict__ W2,            // [2][256] fp32
    const float* __restrict__ b2,            // [2] fp32
    float* __restrict__ out)                 // [4][512][512][2] fp32
{
    __shared__ unsigned short js[64 * S2_LD];
    const int tid  = threadIdx.x;
    const int lane = tid & 63;
    const int wave = tid >> 6;
    const int blk  = blockIdx.x;        // 0..255
    const int b  = blk >> 6;            // 4
    const int iS = (blk >> 3) & 7;      // 8
    const int jS = blk & 7;             // 8
    const int l15 = lane & 15;
    const int quad = lane >> 4;

    // Stage j-rows o[b][jS*64 .. +63][0:256] into LDS (coalesced 16B copies).
    const unsigned short* jbase = o + (b * 512 + jS * 64) * 256;
    #pragma unroll
    for (int i = 0; i < 8; ++i) {
        const int idx = i * 256 + tid;      // 0..2047 = 64 rows x 32 chunks
        const int row = idx >> 5;
        const int c8  = idx & 31;
        *(bf16x8*)(&js[row * S2_LD + c8 * 8]) = *(const bf16x8*)(jbase + row * 256 + c8 * 8);
    }
    __syncthreads();

    const unsigned short* irow = o + ((b * 512 + iS * 64 + wave * 16 + l15) * 256) + quad * 8;
    const float* w20p = W2 + quad * 8;
    const float* w21p = W2 + 256 + quad * 8;

    f32x4 acc0[4], acc1[4];
    #pragma unroll
    for (int g = 0; g < 4; ++g) {
        acc0[g] = (f32x4){0.f, 0.f, 0.f, 0.f};
        acc1[g] = (f32x4){0.f, 0.f, 0.f, 0.f};
    }

    #pragma unroll
    for (int s = 0; s < 8; ++s) {
        const int k = s * 32;
        bf16x8 oi = *(const bf16x8*)(irow + k);
        f32x4 wlo0 = *(const f32x4*)(w20p + k);
        f32x4 whi0 = *(const f32x4*)(w20p + k + 4);
        f32x4 wlo1 = *(const f32x4*)(w21p + k);
        f32x4 whi1 = *(const f32x4*)(w21p + k + 4);
        bf16x8 a0, a1;
        #pragma unroll
        for (int j = 0; j < 4; ++j) {
            const float olo = bf2f((unsigned short)oi[j]);
            const float ohi = bf2f((unsigned short)oi[4 + j]);
            a0[j]     = (short)f2bf(olo * wlo0[j]);
            a0[4 + j] = (short)f2bf(ohi * whi0[j]);
            a1[j]     = (short)f2bf(olo * wlo1[j]);
            a1[4 + j] = (short)f2bf(ohi * whi1[j]);
        }
        #pragma unroll
        for (int g = 0; g < 4; ++g) {
            bf16x8 bj = *(const bf16x8*)(&js[(g * 16 + l15) * S2_LD + k + quad * 8]);
            acc0[g] = __builtin_amdgcn_mfma_f32_16x16x32_bf16(a0, bj, acc0[g], 0, 0, 0);
            acc1[g] = __builtin_amdgcn_mfma_f32_16x16x32_bf16(a1, bj, acc1[g], 0, 0, 0);
        }
    }

    const float bias0 = b2[0];
    const float bias1 = b2[1];
    #pragma unroll
    for (int g = 0; g < 4; ++g) {
        const int j = jS * 64 + g * 16 + l15;           // n-index = lane&15
        #pragma unroll
        for (int r = 0; r < 4; ++r) {
            const int i = iS * 64 + wave * 16 + quad * 4 + r;   // m-index = quad*4+reg
            f32x2 v;
            v[0] = acc0[g][r] + bias0;
            v[1] = acc1[g][r] + bias1;
            *(f32x2*)(out + (((b * 512 + i) * 512) + j) * 2) = v;
        }
    }
}

extern "C" void kernel_launch(void* const* d_in, const int* in_sizes, int n_in,
                              void* d_out, int out_size, void* d_ws, size_t ws_size,
                              hipStream_t stream) {
    const float* x  = (const float*)d_in[0];   // [4,512,1024] fp32
    const float* W1 = (const float*)d_in[1];   // [256,1024] fp32
    const float* b1 = (const float*)d_in[2];   // [256] fp32
    const float* W2 = (const float*)d_in[3];   // [2,256] fp32
    const float* b2 = (const float*)d_in[4];   // [2] fp32
    float* out = (float*)d_out;                // [4,512,512,2] fp32

    // ws layout: o bf16 [2048][256] = 1 MB @ 0; P bf16 [8][2048][256] = 8 MB @ 1 MB
    unsigned short* o = (unsigned short*)d_ws;
    unsigned short* P = (unsigned short*)((char*)d_ws + (1u << 20));

    s1_gemm  <<<512, 256, 0, stream>>>(x, W1, P);
    s1_reduce<<<256, 256, 0, stream>>>(P, b1, o);
    stage2_kernel<<<256, 256, 0, stream>>>(o, W2, b2, out);
}